// Round 7
// baseline (212.492 us; speedup 1.0000x reference)
//
#include <hip/hip_runtime.h>

#define GN   1024
#define GNN  (GN * GN)
#define GP   16
#define NOUT 127          // ys[1:] = T_1 .. T_127
#define TILE 64           // output tile per block
#define KST  16           // fused time steps per launch
#define SZ   96           // TILE + 2*KST (region side)
#define NRB  24           // row-blocks  (SZ/4)
#define NCB  24           // col-blocks  (SZ/4)
#define NTHR 576          // NRB*NCB threads, 9 waves
#define RST  100          // plane row stride (floats), 4-float aligned
#define AXB  (NRB * 2 * RST)            // aux base within plane = 4800
#define AXS  ((NCB + 1) * RST)          // one aux side = 2500
#define PLN  (AXB + 2 * AXS)            // plane floats = 9800 (39.2 KB)

// Exact fp32 constants: DT/dx^2 = 1e-7*1023^2 = 0.1046529, DT/(2dx) = 5.115e-5

__device__ __forceinline__ void coord16(int t, int& c0, int& c1, float& w) {
    // coords = linspace(0, 15, 1024): c = t * 15/1023
    double c = (double)t * (15.0 / 1023.0);
    c0 = (int)c;
    c1 = c0 + 1 > 15 ? 15 : c0 + 1;
    w  = (float)(c - (double)c0);
}

__device__ __forceinline__ float bilin16(const float* __restrict__ m,
                                         int i0, int i1, float wi,
                                         int j0, int j1, float wj) {
    float m00 = m[i0 * GP + j0];
    float m10 = m[i1 * GP + j0];
    float m01 = m[i0 * GP + j1];
    float m11 = m[i1 * GP + j1];
    float r0 = m00 * (1.0f - wi) + m10 * wi;
    float r1 = m01 * (1.0f - wi) + m11 * wi;
    return r0 * (1.0f - wj) + r1 * wj;
}

__device__ __forceinline__ float cellv(float C, float L, float R, float U, float D,
                                       float a2, float k2) {
    // val = C - k2*C*((D-U)+(R-L)) + a2*(U+D+L+R-4C)
    float s   = (D - U) + (R - L);
    float lap = fmaf(-4.0f, C, (U + D) + (L + R));
    return fmaf(a2, lap, fmaf(-k2, C * s, C));
}

// One 4-wide row of cells: verified column shift-select logic (rounds 4-6).
__device__ __forceinline__ float4 rowcell(float4 v, float4 U, float4 D,
                                          float sl, float sr,
                                          float4 a2, float4 k2,
                                          bool isl, bool isr) {
    float L0 = isl ? v.x : sl;
    float C0 = isl ? v.y : v.x;
    float R0 = isl ? v.z : v.y;
    float U0 = isl ? U.y : U.x;
    float D0 = isl ? D.y : D.x;
    float L3 = isr ? v.y : v.z;
    float C3 = isr ? v.z : v.w;
    float R3 = isr ? v.w : sr;
    float U3 = isr ? U.z : U.w;
    float D3 = isr ? D.z : D.w;
    float4 nv;
    nv.x = cellv(C0,  L0,  R0,  U0,  D0,  a2.x, k2.x);
    nv.y = cellv(v.y, v.x, v.z, U.y, D.y, a2.y, k2.y);
    nv.z = cellv(v.z, v.y, v.w, U.z, D.z, a2.z, k2.z);
    nv.w = cellv(C3,  L3,  R3,  U3,  D3,  a2.w, k2.w);
    return nv;
}

// LDS-only barrier (global stores stay in flight; rule #18 fencing).
__device__ __forceinline__ void lds_barrier() {
    __builtin_amdgcn_sched_barrier(0);
    asm volatile("s_waitcnt lgkmcnt(0)" ::: "memory");
    __builtin_amdgcn_s_barrier();
    __builtin_amdgcn_sched_barrier(0);
}

// Clamp-baked, pre-scaled coefficient maps.
__global__ __launch_bounds__(256)
void resize_maps_kernel(const float* __restrict__ alpha,
                        const float* __restrict__ kappa,
                        float* __restrict__ a2map,
                        float* __restrict__ k2map) {
    int idx = blockIdx.x * 256 + threadIdx.x;
    if (idx >= GNN) return;
    int i = idx >> 10;
    int j = idx & (GN - 1);
    int ci = i < 1 ? 1 : (i > GN - 2 ? GN - 2 : i);
    int cj = j < 1 ? 1 : (j > GN - 2 ? GN - 2 : j);
    int i0, i1, j0, j1; float wi, wj;
    coord16(ci, i0, i1, wi);
    coord16(cj, j0, j1, wj);
    a2map[idx] = bilin16(alpha, i0, i1, wi, j0, j1, wj) * 0.1046529f;
    k2map[idx] = bilin16(kappa, i0, i1, wi, j0, j1, wj) * 5.115e-5f;
}

// Temporal-blocked stepper, stale-halo scheme, 4x4 cells/thread.
// LDS per plane: boundary rows (rows 0,3 of each row-block) + transposed
// edge-column aux (the .w / .x columns of each strip, one float4 per reader).
// This removes the stride-4 scalar reads (8-way bank conflict) and the
// unread interior-row writes. Dataflow is operand-identical to round 6:
// istop/isbot read their own plane row (seeded RAW, post-replica afterwards)
// which preserves the t=1 raw-row / t>=2 replica-row semantics exactly.
template <bool USE_WS>
__global__ __launch_bounds__(NTHR)
void fused_steps_kernel(const float* __restrict__ srcp,
                        const float* __restrict__ Aarg,   // a2map or alpha
                        const float* __restrict__ Karg,   // k2map or kappa
                        float* __restrict__ out,
                        int base)
{
    __shared__ float lds[2][PLN];   // 2 x 39.2 KB

    const int tid = threadIdx.x;
    const int rb  = tid / NCB;
    const int cb  = tid - rb * NCB;
    const int r0  = rb * 4;
    const int c4  = cb * 4;

    const int gi0 = blockIdx.y * TILE;
    const int gj0 = blockIdx.x * TILE;
    int oi = gi0 - KST; oi = oi < 0 ? 0 : (oi > GN - SZ ? GN - SZ : oi);
    int oj = gj0 - KST; oj = oj < 0 ? 0 : (oj > GN - SZ ? GN - SZ : oj);
    const int di = gi0 - oi;            // 0, 16, or 32
    const int dj = gj0 - oj;

    const bool istop = (rb == 0), isbot = (rb == NRB - 1);
    const bool isl   = (cb == 0), isr   = (cb == NCB - 1);
    const bool core  = (rb >= (di >> 2)) && (rb < (di >> 2) + 16)
                    && (cb >= (dj >> 2)) && (cb < (dj >> 2) + 16);
    const int  tmax  = NOUT - base;

    const long gbase = (long)(oi + r0) * GN + oj + c4;

    // Plane-relative float offsets
    const int uoff   = (istop ? 0 : (rb * 2 - 1)) * RST + c4;  // up-neighbor row
    const int doff   = (isbot ? (NRB * 2 - 1) : (rb * 2 + 2)) * RST + c4;
    const int w0off  = (rb * 2) * RST + c4;                    // own row 0
    const int w3off  = (rb * 2 + 1) * RST + c4;                // own row 3
    const int sloff  = AXB + cb * RST + rb * 4;                // read: left nb .w col
    const int wsloff = AXB + (cb + 1) * RST + rb * 4;          // write: own .w col
    const int sroff  = AXB + AXS + (cb + 1) * RST + rb * 4;    // read: right nb .x col
    const int wsroff = AXB + AXS + cb * RST + rb * 4;          // write: own .x col

    // Coefficients for own 4 rows
    float4 a2[4], k2[4];
    if (USE_WS) {
        #pragma unroll
        for (int q = 0; q < 4; ++q) {
            a2[q] = *(const float4*)(Aarg + gbase + q * GN);
            k2[q] = *(const float4*)(Karg + gbase + q * GN);
        }
    } else {
        #pragma unroll
        for (int q = 0; q < 4; ++q) {
            int gi = oi + r0 + q;
            int ci = gi < 1 ? 1 : (gi > GN - 2 ? GN - 2 : gi);
            int i0, i1; float wi;
            coord16(ci, i0, i1, wi);
            float av[4], kv[4];
            #pragma unroll
            for (int u = 0; u < 4; ++u) {
                int gj = oj + c4 + u;
                int cj = gj < 1 ? 1 : (gj > GN - 2 ? GN - 2 : gj);
                int j0, j1; float wj;
                coord16(cj, j0, j1, wj);
                av[u] = bilin16(Aarg, i0, i1, wi, j0, j1, wj) * 0.1046529f;
                kv[u] = bilin16(Karg, i0, i1, wi, j0, j1, wj) * 5.115e-5f;
            }
            a2[q] = make_float4(av[0], av[1], av[2], av[3]);
            k2[q] = make_float4(kv[0], kv[1], kv[2], kv[3]);
        }
    }

    // Initial load (RAW rows): seed plane-0 boundary rows + aux columns;
    // V carries the CLAMPED rows (verified round-4 semantics).
    float4 V[4];
    {
        float4 ld0 = *(const float4*)(srcp + gbase);
        float4 ld1 = *(const float4*)(srcp + gbase + GN);
        float4 ld2 = *(const float4*)(srcp + gbase + 2 * GN);
        float4 ld3 = *(const float4*)(srcp + gbase + 3 * GN);
        *(float4*)&lds[0][w0off]  = ld0;
        *(float4*)&lds[0][w3off]  = ld3;
        *(float4*)&lds[0][wsloff] = make_float4(ld0.w, ld1.w, ld2.w, ld3.w);
        *(float4*)&lds[0][wsroff] = make_float4(ld0.x, ld1.x, ld2.x, ld3.x);
        V[0] = istop ? ld1 : ld0;
        V[1] = ld1;
        V[2] = ld2;
        V[3] = isbot ? ld2 : ld3;
    }
    __syncthreads();

    auto step = [&](const float* __restrict__ cur, float* __restrict__ nxt, int t) {
        float4 U  = *(const float4*)(cur + uoff);
        float4 D  = *(const float4*)(cur + doff);
        float4 SL = *(const float4*)(cur + sloff);   // rows 0..3 left scalars
        float4 SR = *(const float4*)(cur + sroff);   // rows 0..3 right scalars

        float4 Uop1 = istop ? U : V[0];
        float4 Dop2 = isbot ? D : V[3];

        float4 NV0 = rowcell(V[0], U,    V[1], SL.x, SR.x, a2[0], k2[0], isl, isr);
        float4 NV1 = rowcell(V[1], Uop1, V[2], SL.y, SR.y, a2[1], k2[1], isl, isr);
        float4 NV2 = rowcell(V[2], V[1], Dop2, SL.z, SR.z, a2[2], k2[2], isl, isr);
        float4 NV3 = rowcell(V[3], V[2], D,    SL.w, SR.w, a2[3], k2[3], isl, isr);
        if (istop) NV0 = NV1;             // replica rows (post-fix, pre-write)
        if (isbot) NV3 = NV2;

        *(float4*)(nxt + w0off)  = NV0;
        *(float4*)(nxt + w3off)  = NV3;
        *(float4*)(nxt + wsloff) = make_float4(NV0.w, NV1.w, NV2.w, NV3.w);
        *(float4*)(nxt + wsroff) = make_float4(NV0.x, NV1.x, NV2.x, NV3.x);

        if (core && t <= tmax) {
            float* slab = out + (long)(base + t - 1) * GNN;
            *(float4*)(slab + gbase)          = NV0;
            *(float4*)(slab + gbase + GN)     = NV1;
            *(float4*)(slab + gbase + 2 * GN) = NV2;
            *(float4*)(slab + gbase + 3 * GN) = NV3;
        }
        V[0] = NV0; V[1] = NV1; V[2] = NV2; V[3] = NV3;
        lds_barrier();
    };

    #pragma unroll 1
    for (int it = 0; it < KST / 2; ++it) {
        step(&lds[0][0], &lds[1][0], 2 * it + 1);
        step(&lds[1][0], &lds[0][0], 2 * it + 2);
    }
}

extern "C" void kernel_launch(void* const* d_in, const int* in_sizes, int n_in,
                              void* d_out, int out_size, void* d_ws, size_t ws_size,
                              hipStream_t stream) {
    const float* u0    = (const float*)d_in[0];
    const float* alpha = (const float*)d_in[1];
    const float* kappa = (const float*)d_in[2];
    float* out = (float*)d_out;

    dim3 grd(GN / TILE, GN / TILE, 1);   // 16x16 = 256 blocks = 1/CU

    bool use_ws = ws_size >= (size_t)2 * GNN * sizeof(float);

    if (use_ws) {
        float* a2map = (float*)d_ws;
        float* k2map = a2map + GNN;
        resize_maps_kernel<<<(GNN + 255) / 256, 256, 0, stream>>>(alpha, kappa, a2map, k2map);
        for (int b = 0; b < NOUT; b += KST) {
            const float* src = (b == 0) ? u0 : out + (long)(b - 1) * GNN;
            fused_steps_kernel<true><<<grd, NTHR, 0, stream>>>(src, a2map, k2map, out, b);
        }
    } else {
        for (int b = 0; b < NOUT; b += KST) {
            const float* src = (b == 0) ? u0 : out + (long)(b - 1) * GNN;
            fused_steps_kernel<false><<<grd, NTHR, 0, stream>>>(src, alpha, kappa, out, b);
        }
    }
}